// Round 1
// baseline (801.586 us; speedup 1.0000x reference)
//
#include <hip/hip_runtime.h>
#include <math.h>

#define HID   256
#define NHEADS 4
#define HDIM   64
#define SEQ  4096
#define BATCH   2

// ---------------------------------------------------------------------------
// GEMM: Y[M][256] = X[M][256] @ W[256][256] + bias   (M = 8192)
// BM=BN=64, BK=16, 256 threads, 4x4 micro-tile per thread.
// ---------------------------------------------------------------------------
__global__ __launch_bounds__(256)
void gemm_bias_kernel(const float* __restrict__ X, const float* __restrict__ W,
                      const float* __restrict__ bias, float* __restrict__ Y) {
  __shared__ float As[16][68];  // [k][m], padded
  __shared__ float Bs[16][68];  // [k][n], padded
  const int tid = threadIdx.x;
  const int tx = tid & 15, ty = tid >> 4;
  const int m0 = blockIdx.y * 64, n0 = blockIdx.x * 64;

  const int ar = tid >> 2;          // 0..63  (m row)
  const int ac = (tid & 3) * 4;     // 0,4,8,12 (k col group)
  const int br = tid >> 4;          // 0..15  (k row)
  const int bc = (tid & 15) * 4;    // 0..60  (n col group)

  float c[4][4] = {};

  for (int k0 = 0; k0 < HID; k0 += 16) {
    float4 a  = *(const float4*)&X[(size_t)(m0 + ar) * HID + k0 + ac];
    float4 bw = *(const float4*)&W[(size_t)(k0 + br) * HID + n0 + bc];
    As[ac + 0][ar] = a.x;
    As[ac + 1][ar] = a.y;
    As[ac + 2][ar] = a.z;
    As[ac + 3][ar] = a.w;
    *(float4*)&Bs[br][bc] = bw;
    __syncthreads();
#pragma unroll
    for (int kk = 0; kk < 16; ++kk) {
      float4 av = *(const float4*)&As[kk][ty * 4];
      float4 bv = *(const float4*)&Bs[kk][tx * 4];
      float am[4] = {av.x, av.y, av.z, av.w};
      float bn[4] = {bv.x, bv.y, bv.z, bv.w};
#pragma unroll
      for (int i = 0; i < 4; ++i)
#pragma unroll
        for (int j = 0; j < 4; ++j) c[i][j] += am[i] * bn[j];
    }
    __syncthreads();
  }

  float4 bb = *(const float4*)&bias[n0 + tx * 4];
  float bn[4] = {bb.x, bb.y, bb.z, bb.w};
#pragma unroll
  for (int i = 0; i < 4; ++i) {
    float4 r = make_float4(c[i][0] + bn[0], c[i][1] + bn[1],
                           c[i][2] + bn[2], c[i][3] + bn[3]);
    *(float4*)&Y[(size_t)(m0 + ty * 4 + i) * HID + n0 + tx * 4] = r;
  }
}

// ---------------------------------------------------------------------------
// Flash attention (fp32), one block per (64 queries, batch*head).
// Q rows owned by thread: ty + 16*i ; S key cols: tx + 16*j ; O d cols: tx*4+j.
// KSs buffer holds the K tile during S-compute, then the P tile for PV.
// ---------------------------------------------------------------------------
__global__ __launch_bounds__(256)
void flash_attn_kernel(const float* __restrict__ Qp, const float* __restrict__ Kp,
                       const float* __restrict__ Vp, const int* __restrict__ mask,
                       float* __restrict__ Ao) {
  __shared__ float Qs[64][68];
  __shared__ float KSs[64][68];  // K tile, then P tile
  __shared__ float Vs[64][68];
  __shared__ int   km[64];

  const int tid = threadIdx.x;
  const int tx = tid & 15, ty = tid >> 4;
  const int bh = blockIdx.y;
  const int b = bh >> 2, h = bh & 3;
  const int q0 = blockIdx.x * 64;
  const int qbase = b * SEQ + q0;    // row index base into Qp/Ao
  const int kvbase = b * SEQ;        // row index base into Kp/Vp
  const int coff = h * HDIM;

  // load Q tile, pre-scaled by 1/sqrt(HDIM) = 1/8
  {
    const int r  = tid >> 2;         // 0..63
    const int cg = (tid & 3) * 4;    // need 4 chunks per row -> 4 iterations
#pragma unroll
    for (int it = 0; it < 4; ++it) {
      int id = it * 256 + tid;
      int rr = id >> 4;              // 0..63
      int cc = (id & 15) * 4;        // 0..60
      float4 v = *(const float4*)&Qp[(size_t)(qbase + rr) * HID + coff + cc];
      v.x *= 0.125f; v.y *= 0.125f; v.z *= 0.125f; v.w *= 0.125f;
      *(float4*)&Qs[rr][cc] = v;
    }
    (void)r; (void)cg;
  }

  float o[4][4] = {};
  float m_i[4], l_i[4];
#pragma unroll
  for (int i = 0; i < 4; ++i) { m_i[i] = -1e30f; l_i[i] = 0.f; }

  for (int t = 0; t < SEQ / 64; ++t) {
    const int k0 = t * 64;
    // load K and V tiles
#pragma unroll
    for (int it = 0; it < 4; ++it) {
      int id = it * 256 + tid;
      int rr = id >> 4;
      int cc = (id & 15) * 4;
      *(float4*)&KSs[rr][cc] = *(const float4*)&Kp[(size_t)(kvbase + k0 + rr) * HID + coff + cc];
      *(float4*)&Vs[rr][cc]  = *(const float4*)&Vp[(size_t)(kvbase + k0 + rr) * HID + coff + cc];
    }
    if (tid < 64) km[tid] = mask[kvbase + k0 + tid];
    __syncthreads();

    // S = Qs @ K^T  (4x4 per thread; rows ty+16i, keys tx+16j)
    float s[4][4] = {};
    for (int d = 0; d < HDIM; d += 4) {
      float4 q4[4], k4[4];
#pragma unroll
      for (int i = 0; i < 4; ++i) q4[i] = *(const float4*)&Qs[ty + 16 * i][d];
#pragma unroll
      for (int j = 0; j < 4; ++j) k4[j] = *(const float4*)&KSs[tx + 16 * j][d];
#pragma unroll
      for (int i = 0; i < 4; ++i) {
#pragma unroll
        for (int j = 0; j < 4; ++j) {
          s[i][j] += q4[i].x * k4[j].x + q4[i].y * k4[j].y +
                     q4[i].z * k4[j].z + q4[i].w * k4[j].w;
        }
      }
    }
    // mask
#pragma unroll
    for (int j = 0; j < 4; ++j) {
      if (km[tx + 16 * j] == 0) {
#pragma unroll
        for (int i = 0; i < 4; ++i) s[i][j] = -1e30f;
      }
    }

    // online softmax; row group = 16 lanes sharing ty
    float alpha[4];
#pragma unroll
    for (int i = 0; i < 4; ++i) {
      float mx = fmaxf(fmaxf(s[i][0], s[i][1]), fmaxf(s[i][2], s[i][3]));
#pragma unroll
      for (int off = 1; off < 16; off <<= 1) mx = fmaxf(mx, __shfl_xor(mx, off));
      float mnew = fmaxf(m_i[i], mx);
      alpha[i] = __expf(m_i[i] - mnew);
      m_i[i] = mnew;
      float rs = 0.f;
#pragma unroll
      for (int j = 0; j < 4; ++j) {
        float e = __expf(s[i][j] - mnew);
        if (s[i][j] < -5e29f) e = 0.f;   // masked
        s[i][j] = e;
        rs += e;
      }
#pragma unroll
      for (int off = 1; off < 16; off <<= 1) rs += __shfl_xor(rs, off);
      l_i[i] = l_i[i] * alpha[i] + rs;
    }
    __syncthreads();   // everyone done reading KSs as K

    // write P into KSs
#pragma unroll
    for (int i = 0; i < 4; ++i)
#pragma unroll
      for (int j = 0; j < 4; ++j) KSs[ty + 16 * i][tx + 16 * j] = s[i][j];
    __syncthreads();

    // O = O*alpha + P @ V   (d cols tx*4+j)
#pragma unroll
    for (int i = 0; i < 4; ++i)
#pragma unroll
      for (int j = 0; j < 4; ++j) o[i][j] *= alpha[i];

    for (int kk = 0; kk < 64; kk += 4) {
      float4 vv[4];
#pragma unroll
      for (int u = 0; u < 4; ++u) vv[u] = *(const float4*)&Vs[kk + u][tx * 4];
#pragma unroll
      for (int i = 0; i < 4; ++i) {
        float4 p4 = *(const float4*)&KSs[ty + 16 * i][kk];
        o[i][0] += p4.x * vv[0].x + p4.y * vv[1].x + p4.z * vv[2].x + p4.w * vv[3].x;
        o[i][1] += p4.x * vv[0].y + p4.y * vv[1].y + p4.z * vv[2].y + p4.w * vv[3].y;
        o[i][2] += p4.x * vv[0].z + p4.y * vv[1].z + p4.z * vv[2].z + p4.w * vv[3].z;
        o[i][3] += p4.x * vv[0].w + p4.y * vv[1].w + p4.z * vv[2].w + p4.w * vv[3].w;
      }
    }
    __syncthreads();   // before next tile overwrites KSs/Vs
  }

  // epilogue: divide by l, store
#pragma unroll
  for (int i = 0; i < 4; ++i) {
    float inv = 1.f / l_i[i];
    float4 r = make_float4(o[i][0] * inv, o[i][1] * inv,
                           o[i][2] * inv, o[i][3] * inv);
    *(float4*)&Ao[(size_t)(qbase + ty + 16 * i) * HID + coff + tx * 4] = r;
  }
}

// ---------------------------------------------------------------------------
extern "C" void kernel_launch(void* const* d_in, const int* in_sizes, int n_in,
                              void* d_out, int out_size, void* d_ws, size_t ws_size,
                              hipStream_t stream) {
  const float* query = (const float*)d_in[0];
  const float* keyv  = (const float*)d_in[1];
  const int*   mask  = (const int*)d_in[2];
  const float* Wq = (const float*)d_in[3];
  const float* bq = (const float*)d_in[4];
  const float* Wk = (const float*)d_in[5];
  const float* bk = (const float*)d_in[6];
  const float* Wv = (const float*)d_in[7];
  const float* bv = (const float*)d_in[8];
  const float* Wo = (const float*)d_in[9];
  const float* bo = (const float*)d_in[10];
  float* out = (float*)d_out;

  const int M = BATCH * SEQ;  // 8192
  float* qp = (float*)d_ws;
  float* kp = qp + (size_t)M * HID;
  float* vp = kp + (size_t)M * HID;
  float* ao = vp + (size_t)M * HID;   // total 32 MB of ws

  dim3 blk(256);
  dim3 ggrid(HID / 64, M / 64);       // (4, 128)
  hipLaunchKernelGGL(gemm_bias_kernel, ggrid, blk, 0, stream, query, Wq, bq, qp);
  hipLaunchKernelGGL(gemm_bias_kernel, ggrid, blk, 0, stream, keyv,  Wk, bk, kp);
  hipLaunchKernelGGL(gemm_bias_kernel, ggrid, blk, 0, stream, keyv,  Wv, bv, vp);

  dim3 fgrid(SEQ / 64, BATCH * NHEADS);  // (64, 8)
  hipLaunchKernelGGL(flash_attn_kernel, fgrid, blk, 0, stream, qp, kp, vp, mask, ao);

  hipLaunchKernelGGL(gemm_bias_kernel, ggrid, blk, 0, stream, ao, Wo, bo, out);
}

// Round 2
// 293.552 us; speedup vs baseline: 2.7306x; 2.7306x over previous
//
#include <hip/hip_runtime.h>
#include <math.h>

#define HID   256
#define NHEADS 4
#define HDIM   64
#define SEQ  4096
#define BATCH   2
#define MTOK (BATCH * SEQ)   // 8192 tokens

typedef short bf16x8 __attribute__((ext_vector_type(8)));
typedef float f32x4  __attribute__((ext_vector_type(4)));

// float -> bf16 bits, round-to-nearest-even
__device__ __forceinline__ unsigned short f2b(float f) {
  union { float f; unsigned u; } v; v.f = f;
  unsigned r = (v.u + 0x7FFFu + ((v.u >> 16) & 1u)) >> 16;
  return (unsigned short)r;
}

// ---------------------------------------------------------------------------
// GEMM: Y = X[M][256] @ W[256][256] + bias. MODE: 0 = fp32 out,
// 1 = bf16 out (scaled), 2 = bf16 transposed out Yt[n][MTOK] (for V^T).
// BM=BN=64, BK=16, 256 threads, 4x4 micro-tile.
// ---------------------------------------------------------------------------
template <int MODE>
__global__ __launch_bounds__(256)
void gemm_bias_kernel(const float* __restrict__ X, const float* __restrict__ W,
                      const float* __restrict__ bias, void* __restrict__ Yv,
                      float scale) {
  __shared__ float As[16][68];  // [k][m], padded
  __shared__ float Bs[16][68];  // [k][n], padded
  const int tid = threadIdx.x;
  const int tx = tid & 15, ty = tid >> 4;
  const int m0 = blockIdx.y * 64, n0 = blockIdx.x * 64;

  const int ar = tid >> 2;          // 0..63  (m row)
  const int ac = (tid & 3) * 4;     // 0,4,8,12 (k col group)
  const int br = tid >> 4;          // 0..15  (k row)
  const int bc = (tid & 15) * 4;    // 0..60  (n col group)

  float c[4][4] = {};

  for (int k0 = 0; k0 < HID; k0 += 16) {
    float4 a  = *(const float4*)&X[(size_t)(m0 + ar) * HID + k0 + ac];
    float4 bw = *(const float4*)&W[(size_t)(k0 + br) * HID + n0 + bc];
    As[ac + 0][ar] = a.x;
    As[ac + 1][ar] = a.y;
    As[ac + 2][ar] = a.z;
    As[ac + 3][ar] = a.w;
    *(float4*)&Bs[br][bc] = bw;
    __syncthreads();
#pragma unroll
    for (int kk = 0; kk < 16; ++kk) {
      float4 av = *(const float4*)&As[kk][ty * 4];
      float4 bv = *(const float4*)&Bs[kk][tx * 4];
      float am[4] = {av.x, av.y, av.z, av.w};
      float bn[4] = {bv.x, bv.y, bv.z, bv.w};
#pragma unroll
      for (int i = 0; i < 4; ++i)
#pragma unroll
        for (int j = 0; j < 4; ++j) c[i][j] += am[i] * bn[j];
    }
    __syncthreads();
  }

  float4 bb = *(const float4*)&bias[n0 + tx * 4];
  float bn[4] = {bb.x, bb.y, bb.z, bb.w};

  if (MODE == 0) {
    float* Y = (float*)Yv;
#pragma unroll
    for (int i = 0; i < 4; ++i) {
      float4 r = make_float4(c[i][0] + bn[0], c[i][1] + bn[1],
                             c[i][2] + bn[2], c[i][3] + bn[3]);
      *(float4*)&Y[(size_t)(m0 + ty * 4 + i) * HID + n0 + tx * 4] = r;
    }
  } else if (MODE == 1) {
    unsigned short* Y = (unsigned short*)Yv;
#pragma unroll
    for (int i = 0; i < 4; ++i) {
      ushort4 r;
      r.x = f2b((c[i][0] + bn[0]) * scale);
      r.y = f2b((c[i][1] + bn[1]) * scale);
      r.z = f2b((c[i][2] + bn[2]) * scale);
      r.w = f2b((c[i][3] + bn[3]) * scale);
      *(ushort4*)&Y[(size_t)(m0 + ty * 4 + i) * HID + n0 + tx * 4] = r;
    }
  } else {
    // transposed: Yt[n][MTOK]
    unsigned short* Y = (unsigned short*)Yv;
#pragma unroll
    for (int j = 0; j < 4; ++j) {
      ushort4 r;
      r.x = f2b(c[0][j] + bn[j]);
      r.y = f2b(c[1][j] + bn[j]);
      r.z = f2b(c[2][j] + bn[j]);
      r.w = f2b(c[3][j] + bn[j]);
      *(ushort4*)&Y[(size_t)(n0 + tx * 4 + j) * MTOK + m0 + ty * 4] = r;
    }
  }
}

// ---------------------------------------------------------------------------
// Flash attention, bf16 MFMA. One block = 64 queries (4 waves x 16), one
// (batch, head). KV tiles of 64 keys. Layouts (m89/m91/m120-verified):
//   A frag:  A[m=lane&15][k=quad*8+j]   (8 bf16, ds_read_b128)
//   B frag:  B[k=quad*8+j][n=lane&15]
//   C/D:     col=lane&15, row=quad*4+reg
// ---------------------------------------------------------------------------
__global__ __launch_bounds__(256)
void flash_attn_mfma(const unsigned short* __restrict__ Qp,
                     const unsigned short* __restrict__ Kp,
                     const unsigned short* __restrict__ Vtp,
                     const int* __restrict__ mask,
                     float* __restrict__ Ao) {
  __shared__ __align__(16) unsigned short Ks[64][72];       // [key][d] +pad
  __shared__ __align__(16) unsigned short Vt[64][72];       // [d][kk]  +pad
  __shared__ __align__(16) unsigned short Ps[4][16][72];    // per-wave [q][kk]
  __shared__ float mb[64];

  const int tid = threadIdx.x;
  const int w = tid >> 6;            // wave 0..3
  const int lane = tid & 63;
  const int lq = lane & 15;
  const int quad = lane >> 4;
  const int bh = blockIdx.y;
  const int b = bh >> 2, h = bh & 3;
  const int q0 = blockIdx.x * 64;
  const int qbase = b * SEQ + q0;
  const int kvbase = b * SEQ;
  const int coff = h * HDIM;

  // Q fragments in registers for whole kernel (Qp pre-scaled by 1/8)
  bf16x8 qf0, qf1;
  {
    const unsigned short* qrow =
        &Qp[(size_t)(qbase + w * 16 + lq) * HID + coff + quad * 8];
    qf0 = *(const bf16x8*)&qrow[0];
    qf1 = *(const bf16x8*)&qrow[32];
  }

  f32x4 o[4];
#pragma unroll
  for (int c = 0; c < 4; ++c) o[c] = (f32x4){0.f, 0.f, 0.f, 0.f};
  float m_i[4], l_i[4];
#pragma unroll
  for (int r = 0; r < 4; ++r) { m_i[r] = -1e30f; l_i[r] = 0.f; }

  for (int t = 0; t < SEQ / 64; ++t) {
    const int k0 = t * 64;
    // ---- stage K tile [64 keys][64 d] and Vt tile [64 d][64 kk] ----
#pragma unroll
    for (int p = 0; p < 2; ++p) {
      int idx = p * 256 + tid;
      int r = idx >> 3;
      int cg = (idx & 7) * 8;
      *(uint4*)&Ks[r][cg] =
          *(const uint4*)&Kp[(size_t)(kvbase + k0 + r) * HID + coff + cg];
      *(uint4*)&Vt[r][cg] =
          *(const uint4*)&Vtp[(size_t)(coff + r) * MTOK + b * SEQ + k0 + cg];
    }
    if (tid < 64) mb[tid] = mask[kvbase + k0 + tid] ? 0.f : -1e30f;
    __syncthreads();

    // ---- S = Q K^T : 4 key-chunks x 2 k-chunks ----
    f32x4 sc[4];
#pragma unroll
    for (int c = 0; c < 4; ++c) sc[c] = (f32x4){0.f, 0.f, 0.f, 0.f};
#pragma unroll
    for (int c = 0; c < 4; ++c) {
      bf16x8 kb0 = *(const bf16x8*)&Ks[c * 16 + lq][quad * 8];
      bf16x8 kb1 = *(const bf16x8*)&Ks[c * 16 + lq][32 + quad * 8];
      sc[c] = __builtin_amdgcn_mfma_f32_16x16x32_bf16(qf0, kb0, sc[c], 0, 0, 0);
      sc[c] = __builtin_amdgcn_mfma_f32_16x16x32_bf16(qf1, kb1, sc[c], 0, 0, 0);
    }

    float mbias[4];
#pragma unroll
    for (int c = 0; c < 4; ++c) mbias[c] = mb[c * 16 + lq];

    // ---- online softmax; row group = 16 lanes sharing quad ----
#pragma unroll
    for (int r = 0; r < 4; ++r) {
      float s0 = sc[0][r] + mbias[0];
      float s1 = sc[1][r] + mbias[1];
      float s2 = sc[2][r] + mbias[2];
      float s3 = sc[3][r] + mbias[3];
      float mx = fmaxf(fmaxf(s0, s1), fmaxf(s2, s3));
#pragma unroll
      for (int off = 1; off < 16; off <<= 1) mx = fmaxf(mx, __shfl_xor(mx, off));
      float mnew = fmaxf(m_i[r], mx);
      float alpha = __expf(m_i[r] - mnew);
      m_i[r] = mnew;
      float p0 = __expf(s0 - mnew);
      float p1 = __expf(s1 - mnew);
      float p2 = __expf(s2 - mnew);
      float p3 = __expf(s3 - mnew);
      float rs = (p0 + p1) + (p2 + p3);
#pragma unroll
      for (int off = 1; off < 16; off <<= 1) rs += __shfl_xor(rs, off);
      l_i[r] = l_i[r] * alpha + rs;
      o[0][r] *= alpha; o[1][r] *= alpha; o[2][r] *= alpha; o[3][r] *= alpha;
      const int row = quad * 4 + r;
      Ps[w][row][ 0 + lq] = f2b(p0);
      Ps[w][row][16 + lq] = f2b(p1);
      Ps[w][row][32 + lq] = f2b(p2);
      Ps[w][row][48 + lq] = f2b(p3);
    }

    // ---- O += P V : P A-frags (wave-local LDS), V B-frags from Vt ----
    bf16x8 pa0 = *(const bf16x8*)&Ps[w][lq][quad * 8];
    bf16x8 pa1 = *(const bf16x8*)&Ps[w][lq][32 + quad * 8];
#pragma unroll
    for (int c = 0; c < 4; ++c) {
      bf16x8 vb0 = *(const bf16x8*)&Vt[c * 16 + lq][quad * 8];
      bf16x8 vb1 = *(const bf16x8*)&Vt[c * 16 + lq][32 + quad * 8];
      o[c] = __builtin_amdgcn_mfma_f32_16x16x32_bf16(pa0, vb0, o[c], 0, 0, 0);
      o[c] = __builtin_amdgcn_mfma_f32_16x16x32_bf16(pa1, vb1, o[c], 0, 0, 0);
    }
    __syncthreads();  // K/Vt consumed; safe to restage next tile
  }

  // ---- epilogue: divide by l, store fp32 ----
#pragma unroll
  for (int r = 0; r < 4; ++r) {
    float inv = 1.f / l_i[r];
    const size_t row = (size_t)(qbase + w * 16 + quad * 4 + r);
#pragma unroll
    for (int c = 0; c < 4; ++c)
      Ao[row * HID + coff + c * 16 + lq] = o[c][r] * inv;
  }
}

// ---------------------------------------------------------------------------
extern "C" void kernel_launch(void* const* d_in, const int* in_sizes, int n_in,
                              void* d_out, int out_size, void* d_ws, size_t ws_size,
                              hipStream_t stream) {
  const float* query = (const float*)d_in[0];
  const float* keyv  = (const float*)d_in[1];
  const int*   mask  = (const int*)d_in[2];
  const float* Wq = (const float*)d_in[3];
  const float* bq = (const float*)d_in[4];
  const float* Wk = (const float*)d_in[5];
  const float* bk = (const float*)d_in[6];
  const float* Wv = (const float*)d_in[7];
  const float* bv = (const float*)d_in[8];
  const float* Wo = (const float*)d_in[9];
  const float* bo = (const float*)d_in[10];
  float* out = (float*)d_out;

  unsigned short* qp  = (unsigned short*)d_ws;               // bf16 [8192][256]
  unsigned short* kp  = qp + (size_t)MTOK * HID;             // bf16 [8192][256]
  unsigned short* vtp = kp + (size_t)MTOK * HID;             // bf16 [256][8192]
  float*          ao  = (float*)(vtp + (size_t)MTOK * HID);  // fp32 [8192][256]

  dim3 blk(256);
  dim3 ggrid(HID / 64, MTOK / 64);  // (4, 128)
  hipLaunchKernelGGL((gemm_bias_kernel<1>), ggrid, blk, 0, stream,
                     query, Wq, bq, (void*)qp, 0.125f);
  hipLaunchKernelGGL((gemm_bias_kernel<1>), ggrid, blk, 0, stream,
                     keyv, Wk, bk, (void*)kp, 1.0f);
  hipLaunchKernelGGL((gemm_bias_kernel<2>), ggrid, blk, 0, stream,
                     keyv, Wv, bv, (void*)vtp, 1.0f);

  dim3 fgrid(SEQ / 64, BATCH * NHEADS);  // (64, 8)
  hipLaunchKernelGGL(flash_attn_mfma, fgrid, blk, 0, stream,
                     qp, kp, vtp, mask, ao);

  hipLaunchKernelGGL((gemm_bias_kernel<0>), ggrid, blk, 0, stream,
                     ao, Wo, bo, (void*)out, 1.0f);
}

// Round 3
// 230.249 us; speedup vs baseline: 3.4814x; 1.2749x over previous
//
#include <hip/hip_runtime.h>
#include <math.h>

#define HID   256
#define NHEADS  4
#define HDIM   64
#define SEQ  4096
#define BATCH   2
#define MTOK (BATCH * SEQ)          // 8192 tokens
#define LOG2E 1.44269504088896340736f

typedef short bf16x8 __attribute__((ext_vector_type(8)));
typedef float f32x4  __attribute__((ext_vector_type(4)));

// float -> bf16 bits, round-to-nearest-even
__device__ __forceinline__ unsigned short f2b(float f) {
  union { float f; unsigned u; } v; v.f = f;
  return (unsigned short)((v.u + 0x7FFFu + ((v.u >> 16) & 1u)) >> 16);
}
__device__ __forceinline__ float b2f(unsigned short b) {
  union { unsigned u; float f; } v; v.u = ((unsigned)b) << 16; return v.f;
}
__device__ __forceinline__ float exp2_(float x) {
#if __has_builtin(__builtin_amdgcn_exp2f)
  return __builtin_amdgcn_exp2f(x);
#else
  return exp2f(x);
#endif
}

// ---------------------------------------------------------------------------
// fp32 -> bf16 cast, 4 elems/thread
// ---------------------------------------------------------------------------
__global__ __launch_bounds__(256)
void cast_x(const float4* __restrict__ X, ushort4* __restrict__ Y, int n4) {
  int i = blockIdx.x * 256 + threadIdx.x;
  if (i < n4) {
    float4 v = X[i];
    ushort4 r; r.x = f2b(v.x); r.y = f2b(v.y); r.z = f2b(v.z); r.w = f2b(v.w);
    Y[i] = r;
  }
}

// ---------------------------------------------------------------------------
// Weight cast+transpose: Wt[n][k] = W[k][n] * scale.  64x64 LDS tiles.
// blockIdx.y selects which of the 4 weights; Wq gets 0.125*log2e folded in.
// ---------------------------------------------------------------------------
__global__ __launch_bounds__(256)
void cast_wt(const float* __restrict__ W0, const float* __restrict__ W1,
             const float* __restrict__ W2, const float* __restrict__ W3,
             unsigned short* __restrict__ Wt) {
  __shared__ float t[64][65];
  const float* Ws[4] = {W0, W1, W2, W3};
  const float scl[4] = {0.125f * LOG2E, 1.f, 1.f, 1.f};
  const int wsel = blockIdx.y;
  const float* W = Ws[wsel];
  const float s = scl[wsel];
  unsigned short* O = Wt + (size_t)wsel * HID * HID;
  const int kt = (blockIdx.x & 3) * 64, nt = (blockIdx.x >> 2) * 64;
  const int tid = threadIdx.x;
#pragma unroll
  for (int p = 0; p < 4; ++p) {
    int i = p * 256 + tid;
    int r = i >> 4, c4 = (i & 15) * 4;
    *(float4*)&t[r][c4] = *(const float4*)&W[(size_t)(kt + r) * HID + nt + c4];
  }
  __syncthreads();
#pragma unroll
  for (int p = 0; p < 4; ++p) {
    int i = p * 256 + tid;
    int rn = i >> 4, ck = (i & 15) * 4;
    ushort4 o;
    o.x = f2b(t[ck + 0][rn] * s);
    o.y = f2b(t[ck + 1][rn] * s);
    o.z = f2b(t[ck + 2][rn] * s);
    o.w = f2b(t[ck + 3][rn] * s);
    *(ushort4*)&O[(size_t)(nt + rn) * HID + kt + ck] = o;
  }
}

// ---------------------------------------------------------------------------
// MFMA GEMM: Y = A[M][256] @ Bt^T + bias*bscale, Bt is [n][k] bf16.
// MODE: 0 fp32 out, 1 bf16 out, 2 bf16 transposed out Yt[n][MTOK].
// AF32: A is fp32 (convert during LDS staging).
// BM=BN=64, BK=64, 256 threads (4 waves, 2x2), 32x32 per wave.
// ---------------------------------------------------------------------------
template <int MODE, bool AF32>
__global__ __launch_bounds__(256)
void gemm_mfma(const void* __restrict__ Ap, const unsigned short* __restrict__ Bt,
               const float* __restrict__ bias, float bscale, void* __restrict__ Yv) {
  __shared__ __align__(16) unsigned short As[64][72];
  __shared__ __align__(16) unsigned short Bs[64][72];
  const int tid = threadIdx.x;
  const int w = tid >> 6, lane = tid & 63, lq = lane & 15, quad = lane >> 4;
  const int wm = w & 1, wn = w >> 1;
  const int m0 = blockIdx.y * 64, n0 = blockIdx.x * 64;

  f32x4 acc[2][2];
#pragma unroll
  for (int i = 0; i < 2; ++i)
#pragma unroll
    for (int j = 0; j < 2; ++j) acc[i][j] = (f32x4){0.f, 0.f, 0.f, 0.f};

  for (int k0 = 0; k0 < HID; k0 += 64) {
#pragma unroll
    for (int p = 0; p < 2; ++p) {
      int idx = p * 256 + tid;
      int r = idx >> 3, cg = (idx & 7) * 8;
      if (AF32) {
        const float* A = (const float*)Ap;
        float4 f0 = *(const float4*)&A[(size_t)(m0 + r) * HID + k0 + cg];
        float4 f1 = *(const float4*)&A[(size_t)(m0 + r) * HID + k0 + cg + 4];
        ushort4 u0; u0.x = f2b(f0.x); u0.y = f2b(f0.y); u0.z = f2b(f0.z); u0.w = f2b(f0.w);
        ushort4 u1; u1.x = f2b(f1.x); u1.y = f2b(f1.y); u1.z = f2b(f1.z); u1.w = f2b(f1.w);
        *(ushort4*)&As[r][cg] = u0;
        *(ushort4*)&As[r][cg + 4] = u1;
      } else {
        const unsigned short* A = (const unsigned short*)Ap;
        *(uint4*)&As[r][cg] = *(const uint4*)&A[(size_t)(m0 + r) * HID + k0 + cg];
      }
      *(uint4*)&Bs[r][cg] = *(const uint4*)&Bt[(size_t)(n0 + r) * HID + k0 + cg];
    }
    __syncthreads();
#pragma unroll
    for (int ks = 0; ks < 2; ++ks) {
      bf16x8 a0 = *(const bf16x8*)&As[wm * 32 + lq][ks * 32 + quad * 8];
      bf16x8 a1 = *(const bf16x8*)&As[wm * 32 + 16 + lq][ks * 32 + quad * 8];
      bf16x8 b0 = *(const bf16x8*)&Bs[wn * 32 + lq][ks * 32 + quad * 8];
      bf16x8 b1 = *(const bf16x8*)&Bs[wn * 32 + 16 + lq][ks * 32 + quad * 8];
      acc[0][0] = __builtin_amdgcn_mfma_f32_16x16x32_bf16(a0, b0, acc[0][0], 0, 0, 0);
      acc[0][1] = __builtin_amdgcn_mfma_f32_16x16x32_bf16(a0, b1, acc[0][1], 0, 0, 0);
      acc[1][0] = __builtin_amdgcn_mfma_f32_16x16x32_bf16(a1, b0, acc[1][0], 0, 0, 0);
      acc[1][1] = __builtin_amdgcn_mfma_f32_16x16x32_bf16(a1, b1, acc[1][1], 0, 0, 0);
    }
    __syncthreads();
  }

#pragma unroll
  for (int ni = 0; ni < 2; ++ni) {
    const int col = n0 + wn * 32 + ni * 16 + lq;
    const float bv = bias[col] * bscale;
#pragma unroll
    for (int mi = 0; mi < 2; ++mi) {
#pragma unroll
      for (int r = 0; r < 4; ++r) {
        const int m = m0 + wm * 32 + mi * 16 + quad * 4 + r;
        const float val = acc[mi][ni][r] + bv;
        if (MODE == 0)      ((float*)Yv)[(size_t)m * HID + col] = val;
        else if (MODE == 1) ((unsigned short*)Yv)[(size_t)m * HID + col] = f2b(val);
        else                ((unsigned short*)Yv)[(size_t)col * MTOK + m] = f2b(val);
      }
    }
  }
}

// ---------------------------------------------------------------------------
// Flash attention, bf16 MFMA, 128-key tiles, base-2 softmax (log2e folded
// into Wq).  One block = 64 queries (4 waves x 16), one (batch, head).
//   A frag:  A[m=lane&15][k=quad*8+j]   (contiguous, ds_read_b128)
//   B frag:  B[k=quad*8+j][n=lane&15] read from [n][k]-layout LDS
//   C/D:     col=lane&15, row=quad*4+reg
// ---------------------------------------------------------------------------
__global__ __launch_bounds__(256)
void flash_attn_mfma(const unsigned short* __restrict__ Qp,
                     const unsigned short* __restrict__ Kp,
                     const unsigned short* __restrict__ Vtp,
                     const int* __restrict__ mask,
                     float* __restrict__ Ao) {
  __shared__ __align__(16) unsigned short Ks[128][72];    // [key][d]
  __shared__ __align__(16) unsigned short Vt[64][136];    // [d][key]
  __shared__ __align__(16) unsigned short Ps[4][16][136]; // per-wave [q][key]
  __shared__ float mb[128];

  const int tid = threadIdx.x;
  const int w = tid >> 6, lane = tid & 63, lq = lane & 15, quad = lane >> 4;
  const int bh = blockIdx.y;
  const int b = bh >> 2, h = bh & 3;
  const int q0 = blockIdx.x * 64;
  const int qbase = b * SEQ + q0, kvbase = b * SEQ, coff = h * HDIM;

  // Q fragments in registers for the whole kernel (score-scale pre-folded)
  bf16x8 qf0, qf1;
  {
    const unsigned short* qr = &Qp[(size_t)(qbase + w * 16 + lq) * HID + coff + quad * 8];
    qf0 = *(const bf16x8*)&qr[0];
    qf1 = *(const bf16x8*)&qr[32];
  }

  f32x4 o[4];
#pragma unroll
  for (int c = 0; c < 4; ++c) o[c] = (f32x4){0.f, 0.f, 0.f, 0.f};
  float m_i[4], l_i[4];
#pragma unroll
  for (int r = 0; r < 4; ++r) { m_i[r] = -1e30f; l_i[r] = 0.f; }

  for (int t = 0; t < SEQ / 128; ++t) {
    const int k0 = t * 128;
#pragma unroll
    for (int p = 0; p < 4; ++p) {
      int idx = p * 256 + tid;
      int rk = idx >> 3, ck = (idx & 7) * 8;
      *(uint4*)&Ks[rk][ck] =
          *(const uint4*)&Kp[(size_t)(kvbase + k0 + rk) * HID + coff + ck];
      int rv = idx >> 4, cv = (idx & 15) * 8;
      *(uint4*)&Vt[rv][cv] =
          *(const uint4*)&Vtp[(size_t)(coff + rv) * MTOK + kvbase + k0 + cv];
    }
    if (tid < 128) mb[tid] = mask[kvbase + k0 + tid] ? 0.f : -1e30f;
    __syncthreads();

    // ---- S = Q K^T : 8 key-chunks x 2 k-halves ----
    f32x4 sc[8];
#pragma unroll
    for (int c = 0; c < 8; ++c) {
      sc[c] = (f32x4){0.f, 0.f, 0.f, 0.f};
      bf16x8 kb0 = *(const bf16x8*)&Ks[c * 16 + lq][quad * 8];
      bf16x8 kb1 = *(const bf16x8*)&Ks[c * 16 + lq][32 + quad * 8];
      sc[c] = __builtin_amdgcn_mfma_f32_16x16x32_bf16(qf0, kb0, sc[c], 0, 0, 0);
      sc[c] = __builtin_amdgcn_mfma_f32_16x16x32_bf16(qf1, kb1, sc[c], 0, 0, 0);
    }
    float mbias[8];
#pragma unroll
    for (int c = 0; c < 8; ++c) mbias[c] = mb[c * 16 + lq];

    // ---- online softmax (base-2); row group = 16 lanes sharing quad ----
#pragma unroll
    for (int r = 0; r < 4; ++r) {
      float s[8];
      float mx = -1e30f;
#pragma unroll
      for (int c = 0; c < 8; ++c) { s[c] = sc[c][r] + mbias[c]; mx = fmaxf(mx, s[c]); }
#pragma unroll
      for (int off = 1; off < 16; off <<= 1) mx = fmaxf(mx, __shfl_xor(mx, off));
      float mnew = fmaxf(m_i[r], mx);
      float alpha = exp2_(m_i[r] - mnew);
      m_i[r] = mnew;
      const int row = quad * 4 + r;
      float rs = 0.f;
#pragma unroll
      for (int c = 0; c < 8; ++c) {
        unsigned short u = f2b(exp2_(s[c] - mnew));
        Ps[w][row][c * 16 + lq] = u;
        rs += b2f(u);   // l from the SAME rounded values -> unbiased O/l
      }
#pragma unroll
      for (int off = 1; off < 16; off <<= 1) rs += __shfl_xor(rs, off);
      l_i[r] = l_i[r] * alpha + rs;
      o[0][r] *= alpha; o[1][r] *= alpha; o[2][r] *= alpha; o[3][r] *= alpha;
    }

    // ---- O += P V ----
#pragma unroll
    for (int i = 0; i < 4; ++i) {
      bf16x8 pa = *(const bf16x8*)&Ps[w][lq][i * 32 + quad * 8];
#pragma unroll
      for (int c = 0; c < 4; ++c) {
        bf16x8 vb = *(const bf16x8*)&Vt[c * 16 + lq][i * 32 + quad * 8];
        o[c] = __builtin_amdgcn_mfma_f32_16x16x32_bf16(pa, vb, o[c], 0, 0, 0);
      }
    }
    __syncthreads();
  }

  // ---- epilogue ----
#pragma unroll
  for (int r = 0; r < 4; ++r) {
    float inv = 1.f / l_i[r];
    const size_t row = (size_t)(qbase + w * 16 + quad * 4 + r);
#pragma unroll
    for (int c = 0; c < 4; ++c)
      Ao[row * HID + coff + c * 16 + lq] = o[c][r] * inv;
  }
}

// ---------------------------------------------------------------------------
extern "C" void kernel_launch(void* const* d_in, const int* in_sizes, int n_in,
                              void* d_out, int out_size, void* d_ws, size_t ws_size,
                              hipStream_t stream) {
  const float* query = (const float*)d_in[0];
  const float* keyv  = (const float*)d_in[1];
  const int*   mask  = (const int*)d_in[2];
  const float* Wq = (const float*)d_in[3];
  const float* bq = (const float*)d_in[4];
  const float* Wk = (const float*)d_in[5];
  const float* bk = (const float*)d_in[6];
  const float* Wv = (const float*)d_in[7];
  const float* bv = (const float*)d_in[8];
  const float* Wo = (const float*)d_in[9];
  const float* bo = (const float*)d_in[10];
  float* out = (float*)d_out;

  unsigned short* qb  = (unsigned short*)d_ws;            // bf16 X_q   4MB
  unsigned short* kvb = qb  + (size_t)MTOK * HID;         // bf16 X_kv  4MB
  unsigned short* wts = kvb + (size_t)MTOK * HID;         // bf16 4x[256][256]
  unsigned short* qp  = wts + (size_t)4 * HID * HID;      // bf16 q     4MB
  unsigned short* kp  = qp  + (size_t)MTOK * HID;         // bf16 k     4MB
  unsigned short* vtp = kp  + (size_t)MTOK * HID;         // bf16 v^T   4MB
  float*          ao  = (float*)(vtp + (size_t)MTOK * HID); // fp32 ao  8MB

  const unsigned short* wq_t = wts;
  const unsigned short* wk_t = wts + 1 * HID * HID;
  const unsigned short* wv_t = wts + 2 * HID * HID;
  const unsigned short* wo_t = wts + 3 * HID * HID;

  dim3 blk(256);
  const int n4 = MTOK * HID / 4;
  hipLaunchKernelGGL(cast_x, dim3(n4 / 256), blk, 0, stream,
                     (const float4*)query, (ushort4*)qb, n4);
  hipLaunchKernelGGL(cast_x, dim3(n4 / 256), blk, 0, stream,
                     (const float4*)keyv, (ushort4*)kvb, n4);
  hipLaunchKernelGGL(cast_wt, dim3(16, 4), blk, 0, stream, Wq, Wk, Wv, Wo, wts);

  dim3 ggrid(HID / 64, MTOK / 64);  // (4, 128)
  hipLaunchKernelGGL((gemm_mfma<1, false>), ggrid, blk, 0, stream,
                     (const void*)qb, wq_t, bq, 0.125f * LOG2E, (void*)qp);
  hipLaunchKernelGGL((gemm_mfma<1, false>), ggrid, blk, 0, stream,
                     (const void*)kvb, wk_t, bk, 1.0f, (void*)kp);
  hipLaunchKernelGGL((gemm_mfma<2, false>), ggrid, blk, 0, stream,
                     (const void*)kvb, wv_t, bv, 1.0f, (void*)vtp);

  dim3 fgrid(SEQ / 64, BATCH * NHEADS);  // (64, 8)
  hipLaunchKernelGGL(flash_attn_mfma, fgrid, blk, 0, stream,
                     qp, kp, vtp, mask, ao);

  hipLaunchKernelGGL((gemm_mfma<0, true>), ggrid, blk, 0, stream,
                     (const void*)ao, wo_t, bo, 1.0f, (void*)out);
}